// Round 11
// baseline (146.781 us; speedup 1.0000x reference)
//
#include <hip/hip_runtime.h>
#include <hip/hip_fp16.h>

// ---------------------------------------------------------------------------
// TFN-lite layer, MI355X, round 18. Three dispatches:
//   memset(cnt) -> prep_all(table build + geometry scatter) -> tfn_node.
//
//  R18 = R12 (best 134.1 us; node 44.5 us, VALUBusy 62%, stall ~60%/round on
//  10x16B gathered T-row loads) + ZERO-VGPR T prefetch via global_load_lds:
//  * Per round, the 10 chunks (A row + B row, 160B/lane, 10KB/wave) for round
//    rd+1 DMA into LDS buffer (rd+1)&1 while round rd computes from buffer
//    rd&1. R16 proved register pipelines kill residency (waves ~ 600/VGPR);
//    global_load_lds holds the in-flight tile in LDS instead: VGPR stays ~60.
//  * Single-wave WG -> no barrier; explicit s_waitcnt vmcnt(0) + sched_barrier
//    fences DMA completion before ds_read (compiler does not track the
//    global_load_lds -> LDS dependency).
//  * Records prefetched 2-ahead in regs (rc/rn/rn2) so j0 for round rd+1 is
//    in hand at issue time. Issue path clamps j0 to [0,TBL-2] (garbage-safe);
//    compute path math bit-identical to R12 (absmax 0.0625 expected exact).
//  * LDS 2x10240B = 20480 -> 8 WGs/CU (vs 11 measured at R12): traded TLP
//    for in-wave overlap that needs no registers.
// ---------------------------------------------------------------------------

#define INV_S3  0.5773502691896258f   // 1/sqrt(3)
#define A0S     0.1767766952966369f   // 1/sqrt(32)
#define A1S     0.27386127875258306f  // sqrt(3)/sqrt(40)
#define S15     3.872983346207417f    // sqrt(15)
#define S5      2.23606797749979f     // sqrt(5)
#define INV_S10 0.31622776601683794f  // 1/sqrt(10)   (cg121 normalized)
#define INV_S30 0.18257418583505536f  // 1/sqrt(30)

#define TBL   2048
#define DMAX  8.0f
#define CAP   64

typedef _Float16 half8 __attribute__((ext_vector_type(8)));
typedef _Float16 half2v __attribute__((ext_vector_type(2)));

// ---------------------------------------------------------------------------
// K1: blocks 0..511 build table rows (one wave per row j); all 2048 blocks
// then grid-stride the geometry scatter.  (R12 verbatim)
__global__ __launch_bounds__(256) void prep_all(
    const float* __restrict__ W1, const float* __restrict__ W2,
    const int* __restrict__ ei, const float* __restrict__ pos,
    _Float16* __restrict__ T, int* __restrict__ cnt,
    float4* __restrict__ srec, int E) {

    __shared__ float hs[4][64];
    int tid = threadIdx.x;
    int wv = tid >> 6, lane = tid & 63;
    int j = blockIdx.x * 4 + wv;

    float hv = 0.f;
    if (j < TBL) {
        float d = (float)j * (DMAX / (float)(TBL - 1));
        float acc = 0.f;
#pragma unroll
        for (int i = 0; i < 16; ++i) {
            float t = d - (float)i * (1.0f / 3.0f);
            float r = __expf(-4.5f * t * t);
            acc = fmaf(r, W1[i * 64 + lane], acc);
        }
        hv = fmaxf(acc, 0.f) * 0.25f;   // /sqrt(16)
    }
    hs[wv][lane] = hv;
    __syncthreads();

    if (j < TBL) {
        int u = lane >> 3, wo = lane & 7;
        int b0 = u * 16 + wo;
        int b4 = 512 + u * 8 + wo;
        float a0 = 0.f, a1 = 0.f, a2 = 0.f, a3 = 0.f, a4 = 0.f;
#pragma unroll 4
        for (int k = 0; k < 64; ++k) {
            float hk = hs[wv][k];
            const float* Wk = W2 + k * 576;
            a0 = fmaf(hk, Wk[b0]       + Wk[b0 + 8],       a0);
            a1 = fmaf(hk, Wk[128 + b0] + Wk[128 + b0 + 8], a1);
            a2 = fmaf(hk, Wk[256 + b0] + Wk[256 + b0 + 8], a2);
            a3 = fmaf(hk, Wk[384 + b0] + Wk[384 + b0 + 8], a3);
            a4 = fmaf(hk, Wk[b4], a4);
        }
        // Interleaved pair layout: pair01[u][wo] at u*16+wo*2, pair23 at +128,
        // w4 at 256+u*8+wo.  Row stride 320 halfs (640 B).
        _Float16* Tr = T + (size_t)j * 320;
        int base = u * 16 + wo * 2;
        Tr[base]           = (_Float16)a0;
        Tr[base + 1]       = (_Float16)a1;
        Tr[128 + base]     = (_Float16)a2;
        Tr[128 + base + 1] = (_Float16)a3;
        Tr[256 + u * 8 + wo] = (_Float16)a4;
    }

    // geometry scatter (depends only on memset(cnt))
    int gtid = blockIdx.x * 256 + tid;
    int gsz = gridDim.x * 256;
    for (int e = gtid; e < E; e += gsz) {
        int row = ei[e];
        int col = ei[E + e];
        float ax = pos[3 * row + 0] - pos[3 * col + 0];
        float ay = pos[3 * row + 1] - pos[3 * col + 1];
        float az = pos[3 * row + 2] - pos[3 * col + 2];
        float d2 = ax * ax + ay * ay + az * az + 1e-12f;
        float invd = rsqrtf(d2);
        float dd = d2 * invd;
        int p = atomicAdd(&cnt[row], 1);
        if (p < CAP) {
            float4 r;
            r.x = ax * invd;
            r.y = ay * invd;
            r.z = az * invd;
            r.w = dd;                         // raw fp32 d -- no quantization
            srec[(size_t)row * CAP + p] = r;
        }
    }
}

// ---------------------------------------------------------------------------
// K2: one wave per block (64 thr), block n = node n.  T rows double-buffered
// in LDS via global_load_lds (async DMA, zero VGPR cost).

// async 16B/lane: per-lane global src, wave-uniform LDS base (+lane*16 by HW)
#define GL16(GP, LP)                                                        \
    __builtin_amdgcn_global_load_lds(                                       \
        (const __attribute__((address_space(1))) unsigned int*)(GP),        \
        (__attribute__((address_space(3))) unsigned int*)(LP), 16, 0, 0)

// issue the 10 chunks (A row + B row) of table row J0N into lbuf[BUF].
// lane l=g*8+u sources chunk(k,u) of edge g's row; lands at seg k + l*16.
#define ISSUE(J0N, BUF) {                                                   \
    const char* rb_ = (const char*)T + (size_t)(J0N) * 640;                 \
    char* lb_ = (char*)lbuf[BUF];                                           \
    GL16(rb_ + o0,        lb_);                                             \
    GL16(rb_ + o0 + 16,   lb_ + 1024);                                      \
    GL16(rb_ + o0 + 256,  lb_ + 2048);                                      \
    GL16(rb_ + o0 + 272,  lb_ + 3072);                                      \
    GL16(rb_ + o4,        lb_ + 4096);                                      \
    GL16(rb_ + o0 + 640,  lb_ + 5120);                                      \
    GL16(rb_ + o0 + 656,  lb_ + 6144);                                      \
    GL16(rb_ + o0 + 896,  lb_ + 7168);                                      \
    GL16(rb_ + o0 + 912,  lb_ + 8192);                                      \
    GL16(rb_ + o4 + 640,  lb_ + 9216); }

#define CLAMPJ(W) max(min((int)((W) * ((float)(TBL - 1) / DMAX)), TBL - 2), 0)

__global__ __launch_bounds__(64) void tfn_node(
    const float* __restrict__ x, const float4* __restrict__ srec,
    const int* __restrict__ cnt, const _Float16* __restrict__ T,
    float* __restrict__ y, int N) {

    __shared__ __align__(16) char lbuf[2][10240];

    int lane = threadIdx.x & 63;
    int n = blockIdx.x;
    if (n >= N) return;

    int g = lane >> 3;
    int u = lane & 7;
    int o0 = u * 32;            // byte offset of pair01 chunk a for lane u
    int o4 = 512 + u * 16;      // byte offset of w4 chunk for lane u
    int kc = cnt[n];
    if (kc > CAP) kc = CAP;
    const float4* recs = srec + (size_t)n * CAP;

    const float* xr = x + (size_t)n * 32;
    float xu  = xr[u];
    float xv0 = xr[8 + 3 * u + 0];
    float xv1 = xr[8 + 3 * u + 1];
    float xv2 = xr[8 + 3 * u + 2];
    _Float16 xuh = (_Float16)xu;                    // loop-invariant coefs
    _Float16 p30 = (_Float16)(xv0 * INV_S3);
    _Float16 p31 = (_Float16)(xv1 * INV_S3);
    _Float16 p32 = (_Float16)(xv2 * INV_S3);

    // V: 32 output channels (final layout). V[z]=scalar z; vec w comp k -> V[8+3w+k].
    float V[32];
#pragma unroll
    for (int z = 0; z < 32; ++z) V[z] = 0.f;

    int rounds = (kc + 7) >> 3;
    if (rounds > 0) {
        float4 rc = recs[g];                 // rec for round 0
        float4 rn = rc;
        if (rounds > 1) rn = recs[8 + g];    // rec for round 1
        ISSUE(CLAMPJ(rc.w), 0);              // round-0 T rows -> buf 0

        for (int rd = 0; rd < rounds; ++rd) {
            // all outstanding DMA (round rd T rows + rec prefetch) complete
            asm volatile("s_waitcnt vmcnt(0)" ::: "memory");
            __builtin_amdgcn_sched_barrier(0);

            // issue round rd+1 T rows into the other buffer (zero VGPR held)
            if (rd + 1 < rounds) { ISSUE(CLAMPJ(rn.w), (rd + 1) & 1); }
            float4 rn2 = rn;
            if (rd + 2 < rounds) rn2 = recs[(rd + 2) * 8 + g];

            // read round rd's chunks from LDS (layout = write layout)
            const char* lb = (const char*)lbuf[rd & 1] + lane * 16;
            half8 A01a = *(const half8*)(lb);
            half8 A01b = *(const half8*)(lb + 1024);
            half8 A23a = *(const half8*)(lb + 2048);
            half8 A23b = *(const half8*)(lb + 3072);
            half8 A4   = *(const half8*)(lb + 4096);
            half8 B01a = *(const half8*)(lb + 5120);
            half8 B01b = *(const half8*)(lb + 6144);
            half8 B23a = *(const half8*)(lb + 7168);
            half8 B23b = *(const half8*)(lb + 8192);
            half8 B4   = *(const half8*)(lb + 9216);

            int slot = rd * 8 + g;
            if (slot < kc) {
                float nx = rc.x, ny = rc.y, nz = rc.z;
                float fj = rc.w * ((float)(TBL - 1) / DMAX);
                int j0c = min((int)fj, TBL - 2);
                float tf = fminf(fj - (float)j0c, 1.0f);
                _Float16 th = (_Float16)tf;

                // geometry (per edge, per u) -- R12 verbatim
                float qu = xv0 * nx + xv1 * ny + xv2 * nz;
                float Y22 = 0.5f * S5 * (3.f * ny * ny - 1.f);
                float Y24 = 0.5f * S15 * (nz * nz - nx * nx);
                float M00 = -Y22 * INV_S30 - Y24 * INV_S10;
                float M11 = 2.f * Y22 * INV_S30;
                float M22 = -Y22 * INV_S30 + Y24 * INV_S10;
                float M01 = (S15 * nx * ny) * INV_S10;
                float M02 = (S15 * nx * nz) * INV_S10;
                float M12 = (S15 * ny * nz) * INV_S10;
                float m0 = M00 * xv0 + M01 * xv1 + M02 * xv2;
                float m1 = M01 * xv0 + M11 * xv1 + M12 * xv2;
                float m2 = M02 * xv0 + M12 * xv1 + M22 * xv2;

                half2v xq;  xq.x = xuh;  xq.y = (_Float16)qu;
                half2v c0;  c0.x = (_Float16)(xu * nx);  c0.y = p30;
                half2v c1;  c1.x = (_Float16)(xu * ny);  c1.y = p31;
                half2v c2;  c2.x = (_Float16)(xu * nz);  c2.y = p32;

                // fp16 lerp (packed): each 32-bit reg = (wA[z], wB[z]) pair
                half8 w01a, w01b, w23a, w23b, w4l;
#pragma unroll
                for (int z = 0; z < 8; ++z) {
                    w01a[z] = A01a[z] + (B01a[z] - A01a[z]) * th;
                    w01b[z] = A01b[z] + (B01b[z] - A01b[z]) * th;
                    w23a[z] = A23a[z] + (B23a[z] - A23a[z]) * th;
                    w23b[z] = A23b[z] + (B23b[z] - A23b[z]) * th;
                    w4l[z]  = A4[z]   + (B4[z]   - A4[z])   * th;
                }

                // t0+t1: V[z] += w0*xu + w1*qu   (one dot2 per z)
#pragma unroll
                for (int z = 0; z < 4; ++z) {
                    half2v pa; pa.x = w01a[2 * z]; pa.y = w01a[2 * z + 1];
                    V[z] = __builtin_amdgcn_fdot2(pa, xq, V[z], false);
                    half2v pb; pb.x = w01b[2 * z]; pb.y = w01b[2 * z + 1];
                    V[4 + z] = __builtin_amdgcn_fdot2(pb, xq, V[4 + z], false);
                }

                // t2+t3: V[8+3z+k] += w2*(xu*nk) + w3*(xvk/sqrt3)
#pragma unroll
                for (int z = 0; z < 4; ++z) {
                    half2v pa; pa.x = w23a[2 * z]; pa.y = w23a[2 * z + 1];
                    int b = 8 + 3 * z;
                    V[b]     = __builtin_amdgcn_fdot2(pa, c0, V[b],     false);
                    V[b + 1] = __builtin_amdgcn_fdot2(pa, c1, V[b + 1], false);
                    V[b + 2] = __builtin_amdgcn_fdot2(pa, c2, V[b + 2], false);
                    half2v pb; pb.x = w23b[2 * z]; pb.y = w23b[2 * z + 1];
                    int b2 = 8 + 3 * (z + 4);
                    V[b2]     = __builtin_amdgcn_fdot2(pb, c0, V[b2],     false);
                    V[b2 + 1] = __builtin_amdgcn_fdot2(pb, c1, V[b2 + 1], false);
                    V[b2 + 2] = __builtin_amdgcn_fdot2(pb, c2, V[b2 + 2], false);
                }

                // t4: f32 (precision-critical path)
#pragma unroll
                for (int z = 0; z < 8; ++z) {
                    float we = (float)w4l[z];
                    V[8 + 3 * z]  = fmaf(m0, we, V[8 + 3 * z]);
                    V[9 + 3 * z]  = fmaf(m1, we, V[9 + 3 * z]);
                    V[10 + 3 * z] = fmaf(m2, we, V[10 + 3 * z]);
                }
            }

            rc = rn;
            rn = rn2;
        }
    }

    // Recursive-halving reduce-scatter over lane bits 4..0 (32 shfls total).
#pragma unroll
    for (int h = 16; h >= 1; h >>= 1) {
        bool hi = (lane & h) != 0;
#pragma unroll
        for (int k = 0; k < h; ++k) {
            float lo = V[k], up = V[k + h];
            float keep = hi ? up : lo;
            float send = hi ? lo : up;
            V[k] = keep + __shfl_xor(send, h, 64);
        }
    }
    V[0] += __shfl_xor(V[0], 32, 64);

    if (lane < 32) {
        float v = V[0] * 0.125f * (lane < 8 ? A0S : A1S);
        if (lane < 8) v = v / (1.0f + __expf(-v));   // silu
        y[(size_t)n * 32 + lane] = v;
    }
}

// ---------------------------------------------------------------------------
extern "C" void kernel_launch(void* const* d_in, const int* in_sizes, int n_in,
                              void* d_out, int out_size, void* d_ws, size_t ws_size,
                              hipStream_t stream) {
    const float* x   = (const float*)d_in[0];
    const float* pos = (const float*)d_in[1];
    const int*   ei  = (const int*)d_in[2];
    const float* W1  = (const float*)d_in[3];
    const float* W2  = (const float*)d_in[4];
    int N = in_sizes[1] / 3;
    int E = in_sizes[2] / 2;

    char* ws = (char*)d_ws;
    size_t off = 0;
    _Float16* T    = (_Float16*)(ws + off); off += (size_t)TBL * 320 * 2;      // 1.31 MB
    int*      cnt  = (int*)(ws + off);      off += (size_t)N * 4;              // 100 KB
    float4*   srec = (float4*)(ws + off);   off += (size_t)N * CAP * 16;       // 25.6 MB

    float* y = (float*)d_out;

    hipMemsetAsync(cnt, 0, (size_t)N * 4, stream);
    hipLaunchKernelGGL(prep_all, dim3(2048), dim3(256), 0, stream,
                       W1, W2, ei, pos, T, cnt, srec, E);
    hipLaunchKernelGGL(tfn_node, dim3(N), dim3(64), 0, stream,
                       x, srec, cnt, T, y, N);
}

// Round 12
// 125.801 us; speedup vs baseline: 1.1668x; 1.1668x over previous
//
#include <hip/hip_runtime.h>
#include <hip/hip_fp16.h>

// ---------------------------------------------------------------------------
// TFN-lite layer, MI355X, round 19. Three dispatches:
//   memset(cnt) -> prep_all(table build + geometry scatter) -> tfn_node.
//
//  R19 vs R12 (best 134.1 us; node 44.5 us latency-bound on 10x16B T-row
//  gathers; R10/R13/R16/R18 all proved latency-hiding state kills residency):
//  * NEAREST-ROW lookup in a 4x finer table (TBL 2048 -> 8192, no lerp):
//    per edge-lane 5x16B gathers (one row) instead of 10 (two rows + lerp).
//    Round ALU drops ~40 packed ops; the dependent-load chain halves.
//    Quantization err ~1.2e-3/weight (same order as fp16 table rounding);
//    predicted absmax 0.1-0.2 vs threshold 0.3575.
//  * prep_all table build restructured for 4x rows at ~same cost: 16 rows
//    per block, W2 row read once per k per block, acc[4][5] per thread
//    (statically unrolled). W2 L2 traffic ~75MB.
//  * Node kernel otherwise R12 verbatim (64-thr WG, grid=N, rec prefetch,
//    dot2 accumulate, reduce-scatter). Hot table span ~2.6MB, L2-resident.
// ---------------------------------------------------------------------------

#define INV_S3  0.5773502691896258f   // 1/sqrt(3)
#define A0S     0.1767766952966369f   // 1/sqrt(32)
#define A1S     0.27386127875258306f  // sqrt(3)/sqrt(40)
#define S15     3.872983346207417f    // sqrt(15)
#define S5      2.23606797749979f     // sqrt(5)
#define INV_S10 0.31622776601683794f  // 1/sqrt(10)   (cg121 normalized)
#define INV_S30 0.18257418583505536f  // 1/sqrt(30)

#define TBL   8192
#define RPB   16                      // table rows built per block
#define DMAX  8.0f
#define CAP   64

typedef _Float16 half8 __attribute__((ext_vector_type(8)));
typedef _Float16 half2v __attribute__((ext_vector_type(2)));

// ---------------------------------------------------------------------------
// K1: blocks 0..TBL/RPB-1 build table rows (16 rows/block, W2 shared across
// rows via per-k broadcast); all 2048 blocks then grid-stride the scatter.
__global__ __launch_bounds__(256) void prep_all(
    const float* __restrict__ W1, const float* __restrict__ W2,
    const int* __restrict__ ei, const float* __restrict__ pos,
    _Float16* __restrict__ T, int* __restrict__ cnt,
    float4* __restrict__ srec, int E) {

    __shared__ float hs[RPB][64];
    int tid = threadIdx.x;
    int wv = tid >> 6, lane = tid & 63;
    int jb = blockIdx.x * RPB;

    if (jb < TBL) {                                  // block-uniform
        // phase A: each wave computes h for 4 rows (lane = hidden channel)
#pragma unroll
        for (int s = 0; s < 4; ++s) {
            int j = jb + wv * 4 + s;
            float d = (float)j * (DMAX / (float)(TBL - 1));
            float acc = 0.f;
#pragma unroll
            for (int i = 0; i < 16; ++i) {
                float t = d - (float)i * (1.0f / 3.0f);
                float r = __expf(-4.5f * t * t);
                acc = fmaf(r, W1[i * 64 + lane], acc);
            }
            hs[wv * 4 + s][lane] = fmaxf(acc, 0.f) * 0.25f;   // /sqrt(16)
        }
        __syncthreads();

        // phase B: wave wv folds W2 for its 4 rows; lane -> (u,wo)
        int u = lane >> 3, wo = lane & 7;
        int b0 = u * 16 + wo;
        int b4 = 512 + u * 8 + wo;
        float a0[4] = {0.f, 0.f, 0.f, 0.f};
        float a1[4] = {0.f, 0.f, 0.f, 0.f};
        float a2[4] = {0.f, 0.f, 0.f, 0.f};
        float a3[4] = {0.f, 0.f, 0.f, 0.f};
        float a4[4] = {0.f, 0.f, 0.f, 0.f};
#pragma unroll 2
        for (int k = 0; k < 64; ++k) {
            const float* Wk = W2 + k * 576;
            float w0 = Wk[b0]       + Wk[b0 + 8];
            float w1 = Wk[128 + b0] + Wk[128 + b0 + 8];
            float w2 = Wk[256 + b0] + Wk[256 + b0 + 8];
            float w3 = Wk[384 + b0] + Wk[384 + b0 + 8];
            float w4 = Wk[b4];
#pragma unroll
            for (int s = 0; s < 4; ++s) {
                float hk = hs[wv * 4 + s][k];
                a0[s] = fmaf(hk, w0, a0[s]);
                a1[s] = fmaf(hk, w1, a1[s]);
                a2[s] = fmaf(hk, w2, a2[s]);
                a3[s] = fmaf(hk, w3, a3[s]);
                a4[s] = fmaf(hk, w4, a4[s]);
            }
        }
        // Interleaved pair layout (R12): pair01 at u*16+wo*2, pair23 at +128,
        // w4 at 256+u*8+wo. Row stride 320 halfs (640 B).
#pragma unroll
        for (int s = 0; s < 4; ++s) {
            int j = jb + wv * 4 + s;
            _Float16* Tr = T + (size_t)j * 320;
            int base = u * 16 + wo * 2;
            Tr[base]             = (_Float16)a0[s];
            Tr[base + 1]         = (_Float16)a1[s];
            Tr[128 + base]       = (_Float16)a2[s];
            Tr[128 + base + 1]   = (_Float16)a3[s];
            Tr[256 + u * 8 + wo] = (_Float16)a4[s];
        }
    }

    // geometry scatter (depends only on memset(cnt)) -- R12 verbatim
    int gtid = blockIdx.x * 256 + tid;
    int gsz = gridDim.x * 256;
    for (int e = gtid; e < E; e += gsz) {
        int row = ei[e];
        int col = ei[E + e];
        float ax = pos[3 * row + 0] - pos[3 * col + 0];
        float ay = pos[3 * row + 1] - pos[3 * col + 1];
        float az = pos[3 * row + 2] - pos[3 * col + 2];
        float d2 = ax * ax + ay * ay + az * az + 1e-12f;
        float invd = rsqrtf(d2);
        float dd = d2 * invd;
        int p = atomicAdd(&cnt[row], 1);
        if (p < CAP) {
            float4 r;
            r.x = ax * invd;
            r.y = ay * invd;
            r.z = az * invd;
            r.w = dd;                         // raw fp32 d
            srec[(size_t)row * CAP + p] = r;
        }
    }
}

// ---------------------------------------------------------------------------
// K2: one wave per block (64 thr), block n = node n (R12 shape).
// Nearest-row weights: j0 = round(fj); 5x16B gathers per edge-lane, no lerp.
__global__ __launch_bounds__(64) void tfn_node(
    const float* __restrict__ x, const float4* __restrict__ srec,
    const int* __restrict__ cnt, const _Float16* __restrict__ T,
    float* __restrict__ y, int N) {

    int lane = threadIdx.x & 63;
    int n = blockIdx.x;
    if (n >= N) return;

    int g = lane >> 3;
    int u = lane & 7;
    int kc = cnt[n];
    if (kc > CAP) kc = CAP;
    const float4* recs = srec + (size_t)n * CAP;

    const float* xr = x + (size_t)n * 32;
    float xu  = xr[u];
    float xv0 = xr[8 + 3 * u + 0];
    float xv1 = xr[8 + 3 * u + 1];
    float xv2 = xr[8 + 3 * u + 2];
    _Float16 xuh = (_Float16)xu;                    // loop-invariant coefs
    _Float16 p30 = (_Float16)(xv0 * INV_S3);
    _Float16 p31 = (_Float16)(xv1 * INV_S3);
    _Float16 p32 = (_Float16)(xv2 * INV_S3);

    // V: 32 output channels (final layout). V[z]=scalar z; vec w comp k -> V[8+3w+k].
    float V[32];
#pragma unroll
    for (int z = 0; z < 32; ++z) V[z] = 0.f;

    int rounds = (kc + 7) >> 3;
    float4 rec = make_float4(0.f, 0.f, 0.f, 0.f);
    if (rounds > 0) rec = recs[g];      // always-safe: CAP slots allocated
    for (int rd = 0; rd < rounds; ++rd) {
        float4 cur = rec;
        int slot = rd * 8 + g;
        if (rd + 1 < rounds) rec = recs[slot + 8];   // prefetch next round
        if (slot < kc) {
            float nx = cur.x, ny = cur.y, nz = cur.z;
            float dd = cur.w;

            float fj = dd * ((float)(TBL - 1) / DMAX);
            int j0 = (int)(fj + 0.5f);               // nearest row
            j0 = min(j0, TBL - 1);

            const _Float16* Ar = T + (size_t)j0 * 320;
            const _Float16* Au = Ar + u * 16;
            half8 w01a = *(const half8*)(Au);
            half8 w01b = *(const half8*)(Au + 8);
            half8 w23a = *(const half8*)(Au + 128);
            half8 w23b = *(const half8*)(Au + 136);
            half8 w4l  = *(const half8*)(Ar + 256 + u * 8);

            // geometry (per edge, per u) -- R12 verbatim
            float qu = xv0 * nx + xv1 * ny + xv2 * nz;   // (xv[u].Y1)/S3
            float Y22 = 0.5f * S5 * (3.f * ny * ny - 1.f);
            float Y24 = 0.5f * S15 * (nz * nz - nx * nx);
            float M00 = -Y22 * INV_S30 - Y24 * INV_S10;
            float M11 = 2.f * Y22 * INV_S30;
            float M22 = -Y22 * INV_S30 + Y24 * INV_S10;
            float M01 = (S15 * nx * ny) * INV_S10;
            float M02 = (S15 * nx * nz) * INV_S10;
            float M12 = (S15 * ny * nz) * INV_S10;
            float m0 = M00 * xv0 + M01 * xv1 + M02 * xv2;
            float m1 = M01 * xv0 + M11 * xv1 + M12 * xv2;
            float m2 = M02 * xv0 + M12 * xv1 + M22 * xv2;

            // packed coefficients
            half2v xq;  xq.x = xuh;  xq.y = (_Float16)qu;
            half2v c0;  c0.x = (_Float16)(xu * nx);  c0.y = p30;
            half2v c1;  c1.x = (_Float16)(xu * ny);  c1.y = p31;
            half2v c2;  c2.x = (_Float16)(xu * nz);  c2.y = p32;

            // t0+t1: V[z] += w0*xu + w1*qu   (one dot2 per z)
#pragma unroll
            for (int z = 0; z < 4; ++z) {
                half2v pa; pa.x = w01a[2 * z]; pa.y = w01a[2 * z + 1];
                V[z] = __builtin_amdgcn_fdot2(pa, xq, V[z], false);
                half2v pb; pb.x = w01b[2 * z]; pb.y = w01b[2 * z + 1];
                V[4 + z] = __builtin_amdgcn_fdot2(pb, xq, V[4 + z], false);
            }

            // t2+t3: V[8+3z+k] += w2*(xu*nk) + w3*(xvk/sqrt3)
#pragma unroll
            for (int z = 0; z < 4; ++z) {
                half2v pa; pa.x = w23a[2 * z]; pa.y = w23a[2 * z + 1];
                int b = 8 + 3 * z;
                V[b]     = __builtin_amdgcn_fdot2(pa, c0, V[b],     false);
                V[b + 1] = __builtin_amdgcn_fdot2(pa, c1, V[b + 1], false);
                V[b + 2] = __builtin_amdgcn_fdot2(pa, c2, V[b + 2], false);
                half2v pb; pb.x = w23b[2 * z]; pb.y = w23b[2 * z + 1];
                int b2 = 8 + 3 * (z + 4);
                V[b2]     = __builtin_amdgcn_fdot2(pb, c0, V[b2],     false);
                V[b2 + 1] = __builtin_amdgcn_fdot2(pb, c1, V[b2 + 1], false);
                V[b2 + 2] = __builtin_amdgcn_fdot2(pb, c2, V[b2 + 2], false);
            }

            // t4: f32 (precision-critical path)
#pragma unroll
            for (int z = 0; z < 8; ++z) {
                float we = (float)w4l[z];
                V[8 + 3 * z]  = fmaf(m0, we, V[8 + 3 * z]);
                V[9 + 3 * z]  = fmaf(m1, we, V[9 + 3 * z]);
                V[10 + 3 * z] = fmaf(m2, we, V[10 + 3 * z]);
            }
        }
    }

    // Recursive-halving reduce-scatter over lane bits 4..0 (32 shfls total).
#pragma unroll
    for (int h = 16; h >= 1; h >>= 1) {
        bool hi = (lane & h) != 0;
#pragma unroll
        for (int k = 0; k < h; ++k) {
            float lo = V[k], up = V[k + h];
            float keep = hi ? up : lo;
            float send = hi ? lo : up;
            V[k] = keep + __shfl_xor(send, h, 64);
        }
    }
    V[0] += __shfl_xor(V[0], 32, 64);

    if (lane < 32) {
        float v = V[0] * 0.125f * (lane < 8 ? A0S : A1S);
        if (lane < 8) v = v / (1.0f + __expf(-v));   // silu
        y[(size_t)n * 32 + lane] = v;
    }
}

// ---------------------------------------------------------------------------
extern "C" void kernel_launch(void* const* d_in, const int* in_sizes, int n_in,
                              void* d_out, int out_size, void* d_ws, size_t ws_size,
                              hipStream_t stream) {
    const float* x   = (const float*)d_in[0];
    const float* pos = (const float*)d_in[1];
    const int*   ei  = (const int*)d_in[2];
    const float* W1  = (const float*)d_in[3];
    const float* W2  = (const float*)d_in[4];
    int N = in_sizes[1] / 3;
    int E = in_sizes[2] / 2;

    char* ws = (char*)d_ws;
    size_t off = 0;
    _Float16* T    = (_Float16*)(ws + off); off += (size_t)TBL * 320 * 2;      // 5.24 MB
    int*      cnt  = (int*)(ws + off);      off += (size_t)N * 4;              // 100 KB
    float4*   srec = (float4*)(ws + off);   off += (size_t)N * CAP * 16;       // 25.6 MB

    float* y = (float*)d_out;

    hipMemsetAsync(cnt, 0, (size_t)N * 4, stream);
    hipLaunchKernelGGL(prep_all, dim3(2048), dim3(256), 0, stream,
                       W1, W2, ei, pos, T, cnt, srec, E);
    hipLaunchKernelGGL(tfn_node, dim3(N), dim3(64), 0, stream,
                       x, srec, cnt, T, y, N);
}